// Round 1
// baseline (399.804 us; speedup 1.0000x reference)
//
#include <hip/hip_runtime.h>

typedef __bf16 bf16;
typedef __bf16 bf16x8 __attribute__((ext_vector_type(8)));
typedef float f32x16 __attribute__((ext_vector_type(16)));

#define B_ROWS 16384
#define N_DIM  4096
#define K_DIM  128

// ---------------------------------------------------------------------------
// Kernel 1: transpose V (4096x128 f32) -> Ut (128x4096 bf16), fused with
// per-column partial sums (for s = V.sum(0)).
// 32 blocks x 256 threads; block handles 128 rows of V.
// ---------------------------------------------------------------------------
__global__ __launch_bounds__(256) void prep_kernel(const float* __restrict__ V,
                                                   float* __restrict__ spart,
                                                   bf16* __restrict__ Ut) {
    __shared__ bf16 tile[128 * 136];   // [col][j], stride 136 keeps 16B alignment
    __shared__ float sp[256];
    const int t = threadIdx.x;
    const int jbase = blockIdx.x * 128;
    const int c  = t & 127;            // column of V this thread reads (fixed)
    const int j0 = t >> 7;             // 0 or 1

    float sacc = 0.f;
#pragma unroll 8
    for (int i = 0; i < 64; ++i) {
        int j = j0 + 2 * i;            // covers 0..127
        float v = V[(size_t)(jbase + j) * K_DIM + c];
        sacc += v;
        tile[c * 136 + j] = (bf16)v;
    }
    sp[t] = sacc;
    __syncthreads();
    if (t < 128) spart[blockIdx.x * 128 + t] = sp[t] + sp[t + 128];

    // write transposed tile: 2 threads per column, 64B each
    const int col = t >> 1, half = t & 1;
#pragma unroll
    for (int i = 0; i < 4; ++i) {
        uint4 d = *(const uint4*)&tile[col * 136 + half * 64 + i * 16];
        *(uint4*)&Ut[(size_t)col * N_DIM + jbase + half * 64 + i * 16] = d;
    }
}

// ---------------------------------------------------------------------------
// Kernel 2: s_k = sum of partials; snorm = ||s||^2  (1 block, 128 threads)
// ---------------------------------------------------------------------------
__global__ __launch_bounds__(128) void finalize_s(const float* __restrict__ spart,
                                                  float* __restrict__ snorm_out) {
    const int t = threadIdx.x;
    float s = 0.f;
#pragma unroll
    for (int b = 0; b < 32; ++b) s += spart[b * 128 + t];
    float sq = s * s;
#pragma unroll
    for (int m = 32; m >= 1; m >>= 1) sq += __shfl_down(sq, m, 64);
    __shared__ float red[2];
    if ((t & 63) == 0) red[t >> 6] = sq;
    __syncthreads();
    if (t == 0) snorm_out[0] = red[0] + red[1];
}

// ---------------------------------------------------------------------------
// Kernel 3: main. BM=32 rows/block (512 blocks), 256 threads = 4 waves.
// Wave w computes the 32x32 tile: rows r0..r0+31, cols w*32..w*32+31 of P=x@V,
// accumulating over N=4096 in BK=64 steps via mfma_f32_32x32x16_bf16.
// Staging pass also accumulates exact fp32 xsum and x·W per thread.
// ---------------------------------------------------------------------------
__global__ __launch_bounds__(256, 2) void fm_main(const float* __restrict__ x,
                                                  const float* __restrict__ W,
                                                  const float* __restrict__ bptr,
                                                  const bf16* __restrict__ Ut,
                                                  const float* __restrict__ snorm_ptr,
                                                  float* __restrict__ out) {
    __shared__ bf16  xs[32 * 72];      // x tile bf16, row stride 72 (+8 pad)
    __shared__ bf16  us[128 * 72];     // Ut tile bf16, col stride 72 (+8 pad)
    __shared__ float redxs[32 * 8];
    __shared__ float redxw[32 * 8];
    __shared__ float rowsq[4 * 32];

    const int t    = threadIdx.x;
    const int wave = t >> 6;
    const int lane = t & 63;
    const int l31  = lane & 31;
    const int h    = lane >> 5;
    const int r0   = blockIdx.x * 32;

    // staging roles
    const int srow = t >> 3;           // 0..31 : x row within block
    const int scg  = t & 7;            // 0..7  : 8-float chunk within 64-col slab
    const int ucol = t >> 1;           // 0..127: Ut column
    const int uhalf = t & 1;           // which 32-element half of the 64 k's

    f32x16 acc;
#pragma unroll
    for (int i = 0; i < 16; ++i) acc[i] = 0.f;

    float xsum_acc = 0.f, xw_acc = 0.f;
    const float* xrow = x + (size_t)(r0 + srow) * N_DIM + scg * 8;
    const bf16*  urow = Ut + (size_t)ucol * N_DIM + uhalf * 32;

    for (int kb = 0; kb < N_DIM; kb += 64) {
        // ---- global loads (before barrier so they overlap prior compute) ----
        float4 a0 = *(const float4*)(xrow + kb);
        float4 a1 = *(const float4*)(xrow + kb + 4);
        float4 w0 = *(const float4*)(W + kb + scg * 8);
        float4 w1 = *(const float4*)(W + kb + scg * 8 + 4);
        const uint4* up = (const uint4*)(urow + kb);
        uint4 u0 = up[0], u1 = up[1], u2 = up[2], u3 = up[3];

        xsum_acc += (a0.x + a0.y + a0.z + a0.w) + (a1.x + a1.y + a1.z + a1.w);
        xw_acc   += a0.x * w0.x + a0.y * w0.y + a0.z * w0.z + a0.w * w0.w
                  + a1.x * w1.x + a1.y * w1.y + a1.z * w1.z + a1.w * w1.w;

        bf16x8 xb;
        xb[0] = (bf16)a0.x; xb[1] = (bf16)a0.y; xb[2] = (bf16)a0.z; xb[3] = (bf16)a0.w;
        xb[4] = (bf16)a1.x; xb[5] = (bf16)a1.y; xb[6] = (bf16)a1.z; xb[7] = (bf16)a1.w;

        __syncthreads();   // previous iter's LDS reads done
        *(bf16x8*)&xs[srow * 72 + scg * 8] = xb;
        uint4* usp = (uint4*)&us[ucol * 72 + uhalf * 32];
        usp[0] = u0; usp[1] = u1; usp[2] = u2; usp[3] = u3;
        __syncthreads();   // tiles visible

        // ---- MFMA: 4 k-steps of 16 ----
#pragma unroll
        for (int ks = 0; ks < 64; ks += 16) {
            bf16x8 af  = *(const bf16x8*)&xs[l31 * 72 + ks + h * 8];
            bf16x8 bfv = *(const bf16x8*)&us[(wave * 32 + l31) * 72 + ks + h * 8];
            acc = __builtin_amdgcn_mfma_f32_32x32x16_bf16(af, bfv, acc, 0, 0, 0);
        }
    }

    // ---- epilogue ----
    redxs[srow * 8 + scg] = xsum_acc;
    redxw[srow * 8 + scg] = xw_acc;

    // per-row sum of squares over this wave's 32 cols.
    // C/D layout: col = lane&31, row = (reg&3) + 8*(reg>>2) + 4*(lane>>5)
#pragma unroll
    for (int r = 0; r < 16; ++r) {
        float s = acc[r] * acc[r];
        s += __shfl_xor(s, 1);
        s += __shfl_xor(s, 2);
        s += __shfl_xor(s, 4);
        s += __shfl_xor(s, 8);
        s += __shfl_xor(s, 16);
        if (l31 == 0) {
            int row = (r & 3) + 8 * (r >> 2) + 4 * h;
            rowsq[wave * 32 + row] = s;
        }
    }
    __syncthreads();

    if (t < 32) {
        float xsum = 0.f, xw = 0.f;
#pragma unroll
        for (int g = 0; g < 8; ++g) { xsum += redxs[t * 8 + g]; xw += redxw[t * 8 + g]; }
        float sq = rowsq[t] + rowsq[32 + t] + rowsq[64 + t] + rowsq[96 + t];
        float snorm = snorm_ptr[0];
        float bv = bptr[0];
        out[r0 + t] = bv + xw + 0.5f * sq - 0.5f * xsum * xsum * snorm;
    }
}

// ---------------------------------------------------------------------------
extern "C" void kernel_launch(void* const* d_in, const int* in_sizes, int n_in,
                              void* d_out, int out_size, void* d_ws, size_t ws_size,
                              hipStream_t stream) {
    const float* x  = (const float*)d_in[0];   // 16384*4096
    const float* W  = (const float*)d_in[1];   // 4096
    const float* bp = (const float*)d_in[2];   // 1
    const float* V  = (const float*)d_in[3];   // 4096*128
    float* out = (float*)d_out;

    char* ws = (char*)d_ws;
    float* snorm = (float*)ws;                       // 4 B
    float* spart = (float*)(ws + 1024);              // 32*128*4 = 16 KB
    bf16*  Ut    = (bf16*)(ws + 32768);              // 128*4096*2 = 1 MB

    hipLaunchKernelGGL(prep_kernel, dim3(32), dim3(256), 0, stream, V, spart, Ut);
    hipLaunchKernelGGL(finalize_s, dim3(1), dim3(128), 0, stream, spart, snorm);
    hipLaunchKernelGGL(fm_main, dim3(512), dim3(256), 0, stream, x, W, bp, Ut, snorm, out);
}

// Round 2
// 392.394 us; speedup vs baseline: 1.0189x; 1.0189x over previous
//
#include <hip/hip_runtime.h>

typedef __bf16 bf16;
typedef __bf16 bf16x8 __attribute__((ext_vector_type(8)));
typedef float f32x16 __attribute__((ext_vector_type(16)));

#define B_ROWS 16384
#define N_DIM  4096
#define K_DIM  128

// ---------------------------------------------------------------------------
// Kernel 1: transpose V (4096x128 f32) -> Ut (128x4096 bf16), fused with
// per-column partial sums (for s = V.sum(0)).
// ---------------------------------------------------------------------------
__global__ __launch_bounds__(256) void prep_kernel(const float* __restrict__ V,
                                                   float* __restrict__ spart,
                                                   bf16* __restrict__ Ut) {
    __shared__ bf16 tile[128 * 136];
    __shared__ float sp[256];
    const int t = threadIdx.x;
    const int jbase = blockIdx.x * 128;
    const int c  = t & 127;
    const int j0 = t >> 7;

    float sacc = 0.f;
#pragma unroll 8
    for (int i = 0; i < 64; ++i) {
        int j = j0 + 2 * i;
        float v = V[(size_t)(jbase + j) * K_DIM + c];
        sacc += v;
        tile[c * 136 + j] = (bf16)v;
    }
    sp[t] = sacc;
    __syncthreads();
    if (t < 128) spart[blockIdx.x * 128 + t] = sp[t] + sp[t + 128];

    const int col = t >> 1, half = t & 1;
#pragma unroll
    for (int i = 0; i < 4; ++i) {
        uint4 d = *(const uint4*)&tile[col * 136 + half * 64 + i * 16];
        *(uint4*)&Ut[(size_t)col * N_DIM + jbase + half * 64 + i * 16] = d;
    }
}

// ---------------------------------------------------------------------------
// Kernel 2: snorm = ||V.sum(0)||^2
// ---------------------------------------------------------------------------
__global__ __launch_bounds__(128) void finalize_s(const float* __restrict__ spart,
                                                  float* __restrict__ snorm_out) {
    const int t = threadIdx.x;
    float s = 0.f;
#pragma unroll
    for (int b = 0; b < 32; ++b) s += spart[b * 128 + t];
    float sq = s * s;
#pragma unroll
    for (int m = 32; m >= 1; m >>= 1) sq += __shfl_down(sq, m, 64);
    __shared__ float red[2];
    if ((t & 63) == 0) red[t >> 6] = sq;
    __syncthreads();
    if (t == 0) snorm_out[0] = red[0] + red[1];
}

// ---------------------------------------------------------------------------
// Kernel 3: main. BM=32 rows/block, 512 blocks, 256 threads = 4 waves.
// Double-buffered LDS, 1 barrier/iter:
//   iter i: store x regs (tile i) -> xs[b]; barrier (also drains DMA us[b]);
//           issue DMA us[b^1] (tile i+1) + x reg prefetch (tile i+1);
//           xsum/xw VALU on tile-i regs; MFMA on xs[b]/us[b].
// Ut staged via global_load_lds width=16 (unpadded layout, wave-uniform base).
// ---------------------------------------------------------------------------
__global__ __launch_bounds__(256, 2) void fm_main(const float* __restrict__ x,
                                                  const float* __restrict__ W,
                                                  const float* __restrict__ bptr,
                                                  const bf16* __restrict__ Ut,
                                                  const float* __restrict__ snorm_ptr,
                                                  float* __restrict__ out) {
    __shared__ bf16  xs[2][32 * 72];      // padded (+8) x tile, bf16
    __shared__ bf16  us[2][128 * 64];     // unpadded Ut tile (global_load_lds dest)
    __shared__ float redxs[256];
    __shared__ float redxw[256];
    __shared__ float rowsq[4 * 32];

    const int t    = threadIdx.x;
    const int wave = t >> 6;
    const int lane = t & 63;
    const int l31  = lane & 31;
    const int h    = lane >> 5;
    const int r0   = blockIdx.x * 32;

    const int srow = t >> 3;              // 0..31 x row
    const int scg  = t & 7;               // 0..7 chunk of 8 floats

    f32x16 acc;
#pragma unroll
    for (int i = 0; i < 16; ++i) acc[i] = 0.f;

    float xsum_acc = 0.f, xw_acc = 0.f;
    const float* xrow = x + (size_t)(r0 + srow) * N_DIM + scg * 8;
    const float* wrow = W + scg * 8;
    // DMA source: lane covers (col_local = lane>>3, kchunk = lane&7)
    const bf16* ub = Ut + (size_t)(wave * 32 + (lane >> 3)) * N_DIM + (lane & 7) * 8;

    // ---- prologue: tile 0 ----
    float4 a0 = *(const float4*)(xrow);
    float4 a1 = *(const float4*)(xrow + 4);
    float4 w0 = *(const float4*)(wrow);
    float4 w1 = *(const float4*)(wrow + 4);
#pragma unroll
    for (int j = 0; j < 4; ++j) {
        __builtin_amdgcn_global_load_lds(
            (const __attribute__((address_space(1))) void*)(ub + (size_t)j * 8 * N_DIM),
            (__attribute__((address_space(3))) void*)&us[0][(wave * 32 + j * 8) * 64],
            16, 0, 0);
    }

    for (int it = 0; it < 64; ++it) {
        const int b = it & 1;
        const int kb_next = (it < 63) ? (it + 1) * 64 : 0;  // clamp: harmless reload

        // ---- store x regs (tile it) into xs[b] ----
        bf16x8 xb;
        xb[0] = (bf16)a0.x; xb[1] = (bf16)a0.y; xb[2] = (bf16)a0.z; xb[3] = (bf16)a0.w;
        xb[4] = (bf16)a1.x; xb[5] = (bf16)a1.y; xb[6] = (bf16)a1.z; xb[7] = (bf16)a1.w;
        *(bf16x8*)&xs[b][srow * 72 + scg * 8] = xb;

        __syncthreads();   // xs[b] + DMA'd us[b] visible; prior readers of [b^1] done

        // ---- prefetch tile it+1 ----
        float4 na0 = *(const float4*)(xrow + kb_next);
        float4 na1 = *(const float4*)(xrow + kb_next + 4);
        float4 nw0 = *(const float4*)(wrow + kb_next);
        float4 nw1 = *(const float4*)(wrow + kb_next + 4);
#pragma unroll
        for (int j = 0; j < 4; ++j) {
            __builtin_amdgcn_global_load_lds(
                (const __attribute__((address_space(1))) void*)(ub + (size_t)j * 8 * N_DIM + kb_next),
                (__attribute__((address_space(3))) void*)&us[b ^ 1][(wave * 32 + j * 8) * 64],
                16, 0, 0);
        }

        // ---- exact fp32 side computations on tile-it regs ----
        xsum_acc += (a0.x + a0.y + a0.z + a0.w) + (a1.x + a1.y + a1.z + a1.w);
        xw_acc   += a0.x * w0.x + a0.y * w0.y + a0.z * w0.z + a0.w * w0.w
                  + a1.x * w1.x + a1.y * w1.y + a1.z * w1.z + a1.w * w1.w;

        // ---- MFMA on buffer b ----
#pragma unroll
        for (int ks = 0; ks < 64; ks += 16) {
            bf16x8 af  = *(const bf16x8*)&xs[b][l31 * 72 + ks + h * 8];
            bf16x8 bfv = *(const bf16x8*)&us[b][(wave * 32 + l31) * 64 + ks + h * 8];
            acc = __builtin_amdgcn_mfma_f32_32x32x16_bf16(af, bfv, acc, 0, 0, 0);
        }

        a0 = na0; a1 = na1; w0 = nw0; w1 = nw1;
    }

    // ---- epilogue ----
    redxs[t] = xsum_acc;
    redxw[t] = xw_acc;

    // per-row sum of squares over this wave's 32 cols.
    // C/D layout: col = lane&31, row = (reg&3) + 8*(reg>>2) + 4*(lane>>5)
#pragma unroll
    for (int r = 0; r < 16; ++r) {
        float s = acc[r] * acc[r];
        s += __shfl_xor(s, 1);
        s += __shfl_xor(s, 2);
        s += __shfl_xor(s, 4);
        s += __shfl_xor(s, 8);
        s += __shfl_xor(s, 16);
        if (l31 == 0) {
            int row = (r & 3) + 8 * (r >> 2) + 4 * h;
            rowsq[wave * 32 + row] = s;
        }
    }
    __syncthreads();

    if (t < 32) {
        float xsum = 0.f, xw = 0.f;
#pragma unroll
        for (int g = 0; g < 8; ++g) { xsum += redxs[t * 8 + g]; xw += redxw[t * 8 + g]; }
        float sq = rowsq[t] + rowsq[32 + t] + rowsq[64 + t] + rowsq[96 + t];
        float snorm = snorm_ptr[0];
        float bv = bptr[0];
        out[r0 + t] = bv + xw + 0.5f * sq - 0.5f * xsum * xsum * snorm;
    }
}

// ---------------------------------------------------------------------------
extern "C" void kernel_launch(void* const* d_in, const int* in_sizes, int n_in,
                              void* d_out, int out_size, void* d_ws, size_t ws_size,
                              hipStream_t stream) {
    const float* x  = (const float*)d_in[0];
    const float* W  = (const float*)d_in[1];
    const float* bp = (const float*)d_in[2];
    const float* V  = (const float*)d_in[3];
    float* out = (float*)d_out;

    char* ws = (char*)d_ws;
    float* snorm = (float*)ws;                 // 4 B
    float* spart = (float*)(ws + 1024);        // 16 KB
    bf16*  Ut    = (bf16*)(ws + 32768);        // 1 MB

    hipLaunchKernelGGL(prep_kernel, dim3(32), dim3(256), 0, stream, V, spart, Ut);
    hipLaunchKernelGGL(finalize_s, dim3(1), dim3(128), 0, stream, spart, snorm);
    hipLaunchKernelGGL(fm_main, dim3(512), dim3(256), 0, stream, x, W, bp, Ut, snorm, out);
}